// Round 15
// baseline (508.495 us; speedup 1.0000x reference)
//
#include <hip/hip_runtime.h>
#include <math.h>

// B=32, R=16384, C=16, IC=16, OC=16, 3 routing iterations.
// x: (B,C,IC) fp32 [8192]; W: (R,C,OC,IC) fp32 [67108864 = 256 MB]; out: (B,C,OC) fp32.
//
// Algebra: logits are linear in v with the same u_hat each pass:
//   L2 = <u, v1>,  L3 = L2 + <u, v2> = <u, v1 + v2>
// so pass 3 is the SAME kernel as pass 2 fed with vs = v1 + v2 -> no L history.
//
// R15: DENSE-STREAM blocks.  R10-R14 varied occupancy, ring depth, barriers,
// coalescing -- k_iter pinned at ~76-90us = 3.4 TB/s, while k_wsum moves the
// same 256 MB at 5.7 TB/s.  Remaining difference: k_wsum's grid sweeps W as
// dense contiguous slabs; every k_iter gave blocks a c-column (1 KB per
// 16 KB stride), so DRAM row locality relied on 16 uncoordinated blocks.
// Now: 256 blocks x 1024 threads (1/CU, 16 waves); block bx = rows
// [64bx,64bx+64) x ALL 16 c; wave wv <-> c = wv (per-wave state = R14's
// proven footprint).  Per 2-row chunk the block's 16 waves stage a
// contiguous 32 KB slab.  Wave-private FIFOs kept: counted vmcnt(2), ring-2,
// ZERO barriers in the entire kernel (vf/E/Z direct to global).

typedef __attribute__((ext_vector_type(8)))  short short8;
typedef __attribute__((ext_vector_type(16))) float f32x16;

union FU { short8 s; unsigned int u[4]; };

typedef const __attribute__((address_space(1))) void GV;
typedef __attribute__((address_space(3))) void LV;

// Split two fp32 into packed bf16 (hi, lo) pairs: hi = RNE-bf16; lo covers
// the next 16 bits (round-half-up).  Product w*x reconstructed with 4 MFMA
// terms -> residual ~2^-16 relative.
__device__ __forceinline__ void splitpk(float a, float b,
                                        unsigned int& hp, unsigned int& lp) {
    unsigned int ua = __float_as_uint(a), ub = __float_as_uint(b);
    unsigned int ta = ua + 0x7FFFu + ((ua >> 16) & 1u);   // RNE to bf16
    unsigned int tb = ub + 0x7FFFu + ((ub >> 16) & 1u);
    hp = (ta >> 16) | (tb & 0xFFFF0000u);                 // (hi_b<<16)|hi_a
    float ha = __uint_as_float(ta & 0xFFFF0000u);
    float hb = __uint_as_float(tb & 0xFFFF0000u);
    unsigned int la = __float_as_uint(a - ha) + 0x8000u;  // round-half-up
    unsigned int lb = __float_as_uint(b - hb) + 0x8000u;
    lp = (la >> 16) | (lb & 0xFFFF0000u);
}

// ---------------------------------------------------------------------------
// K0: zero the accumulator region (wsum+E2+Z2+E3+Z3 = 21504 floats).
// ---------------------------------------------------------------------------
__global__ __launch_bounds__(256) void k_zero(float* __restrict__ ws) {
    ws[blockIdx.x * 256 + threadIdx.x] = 0.f;      // grid 84 x 256 = 21504
}

// ---------------------------------------------------------------------------
// K1: wsum[c,o,i] = sum_r W[r,c,o,i].  W = 16,777,216 float4s.
// ---------------------------------------------------------------------------
__global__ __launch_bounds__(256) void k_wsum(const float4* __restrict__ W4,
                                              float* __restrict__ wsum) {
    int gid = blockIdx.x * 256 + threadIdx.x;      // [0, 262144)
    float4 acc = {0.f, 0.f, 0.f, 0.f};
    int idx = gid;
    #pragma unroll
    for (int it = 0; it < 64; ++it) {              // 16777216 / 262144 = 64
        float4 w = W4[idx];
        acc.x += w.x; acc.y += w.y; acc.z += w.z; acc.w += w.w;
        idx += 262144;
    }
    int cls = gid & 1023;                          // (c,o,i4) within an r-block
    atomicAdd(&wsum[cls * 4 + 0], acc.x);
    atomicAdd(&wsum[cls * 4 + 1], acc.y);
    atomicAdd(&wsum[cls * 4 + 2], acc.z);
    atomicAdd(&wsum[cls * 4 + 3], acc.w);
}

// ---------------------------------------------------------------------------
// K2: s1 = (1/R) * wsum . x ;  v1 = squash(s1)  -> v1[b*256 + c*16 + o]
// ---------------------------------------------------------------------------
__global__ __launch_bounds__(256) void k_v1(const float* __restrict__ wsum,
                                            const float* __restrict__ x,
                                            float* __restrict__ v1) {
    int t = blockIdx.x * 256 + threadIdx.x;        // 0..8191
    int o = t & 15, c = (t >> 4) & 15, b = t >> 8;
    const float* xb = x + (b * 16 + c) * 16;
    const float* wr = wsum + (c * 16 + o) * 16;
    float s = 0.f;
    #pragma unroll
    for (int i = 0; i < 16; ++i) s += wr[i] * xb[i];
    s *= (1.0f / 16384.0f);
    float ns = s * s;
    #pragma unroll
    for (int d = 1; d < 16; d <<= 1) ns += __shfl_xor(ns, d);
    v1[t] = s * (sqrtf(ns) / (1.0f + ns));
}

// ---------------------------------------------------------------------------
// K4a: v2 = squash(E/Z); vs = v1 + v2   (input to pass 3)
// ---------------------------------------------------------------------------
__global__ __launch_bounds__(256) void k_vout_vs(const float* __restrict__ E,
                                                 const float* __restrict__ Z,
                                                 const float* __restrict__ v1,
                                                 float* __restrict__ vs) {
    int t = blockIdx.x * 256 + threadIdx.x;        // 0..8191
    float s = E[t] / Z[t >> 4];                    // t>>4 = b*16+c
    float ns = s * s;
    #pragma unroll
    for (int d = 1; d < 16; d <<= 1) ns += __shfl_xor(ns, d);
    vs[t] = v1[t] + s * (sqrtf(ns) / (1.0f + ns));
}

// ---------------------------------------------------------------------------
// K4b: out = squash(E/Z)
// ---------------------------------------------------------------------------
__global__ __launch_bounds__(256) void k_vout(const float* __restrict__ E,
                                              const float* __restrict__ Z,
                                              float* __restrict__ dst) {
    int t = blockIdx.x * 256 + threadIdx.x;        // 0..8191
    float s = E[t] / Z[t >> 4];
    float ns = s * s;
    #pragma unroll
    for (int d = 1; d < 16; d <<= 1) ns += __shfl_xor(ns, d);
    dst[t] = s * (sqrtf(ns) / (1.0f + ns));
}

// ---------------------------------------------------------------------------
// K3: MFMA routing pass, dense-stream blocks.
//   Block bx: rows [64bx, +64) x ALL 16 c; 1024 threads = 16 waves; wave
//   wv <-> c = wv.  32 chunks of 2 rows.  Per (wave, chunk):
//   A (M=32 x K=16): lane m=l&31 -> (r'=m>>4, o=m&15); k-slice i=8*(l>>5)+j.
//   B (K=16 x N=32): lane n=b, chunk-invariant (x in regs).
//   C: col=lane&31=b; row-reg o=(reg&3)+4hi+8((reg>>2)&1), r'=reg>>3
//   [verified R10].  Lv = 8 in-lane FMAs + ONE shfl_xor(32).
// Staging: wave wv stages its 2 rows (r', c=wv) of chunk k as 2 x 1 KB
// coalesced global_load_lds; the block's 16 waves jointly cover 32 KB of
// CONSECUTIVE addresses per chunk (k_wsum-density).  LDS [slot][c*2+r'][65]
// padded rows -> fragment ds_read_b128 group = 2c+(m>>4)+4(m&1)+2hi+n =
// all 8 granule-groups x 8 lanes (conflict-free).  Wave-private ring-2,
// counted vmcnt(2); NO barriers anywhere (vf from global; E/Z atomics).
// ---------------------------------------------------------------------------
__global__ __launch_bounds__(1024)
void k_iter(const float* __restrict__ W,
            const float* __restrict__ x,
            const float* __restrict__ v,
            float* __restrict__ E,
            float* __restrict__ Z) {
    __shared__ float4 Wr[2 * 2080];                // 2 slots x 32 rows x 65 f4 (66.5 KB)

    int tid = threadIdx.x, wv = tid >> 6, l = tid & 63;
    int m  = l & 31;                               // A-row / b-col
    int hi = l >> 5;                               // k-slice select
    int c  = wv;                                   // wave-private capsule
    int r0 = blockIdx.x * 64;

    // B-fragment (x), chunk-invariant: lane b=m, i = 8*hi + 0..7
    FU bh, bl;
    {
        const float4* xb = (const float4*)x + m * 64 + c * 4 + hi * 2;
        float4 x0 = xb[0], x1 = xb[1];
        splitpk(x0.x, x0.y, bh.u[0], bl.u[0]);
        splitpk(x0.z, x0.w, bh.u[1], bl.u[1]);
        splitpk(x1.x, x1.y, bh.u[2], bl.u[2]);
        splitpk(x1.z, x1.w, bh.u[3], bl.u[3]);
    }

    // v-fragment matching C rows: vf[reg] = v[b=m][c][o(reg)]  (one-time)
    float vf[16];
    #pragma unroll
    for (int reg = 0; reg < 16; ++reg) {
        int o = (reg & 3) + 4 * hi + 8 * ((reg >> 2) & 1);
        vf[reg] = v[m * 256 + c * 16 + o];
    }

    float accE[16];
    #pragma unroll
    for (int reg = 0; reg < 16; ++reg) accE[reg] = 0.f;
    float accZ = 0.f;

    // pin vmcnt=0 so the counted waits below are exact (x/v loads retired)
    asm volatile("s_waitcnt vmcnt(0)" ::: "memory");

    const float4* W4 = (const float4*)W;

    // STAGE: wave wv=c stages rows {2cn, 2cn+1} at its c: 2 x 1 KB coalesced
    // (lane l -> f4 l); dest = padded LDS rows (c*2+r')*65.
#define STAGE(sl, cn) {                                                        \
        const float4* s0 = W4 + (size_t)(r0 + (cn) * 2) * 1024 + c * 64 + l;   \
        __builtin_amdgcn_global_load_lds((GV*)s0,                              \
            (LV*)&Wr[(sl) * 2080 + (c * 2 + 0) * 65], 16, 0, 0);               \
        __builtin_amdgcn_global_load_lds((GV*)(s0 + 1024),                     \
            (LV*)&Wr[(sl) * 2080 + (c * 2 + 1) * 65], 16, 0, 0);               \
    }

    STAGE(0, 0); STAGE(1, 1);                      // 4 issues (4 KB/wave) in flight

    // fragment read base: row (c*2 + r'), r'=m>>4; elem (m&15)*4 + 2hi (+n)
    int rbase = (c * 2 + (m >> 4)) * 65 + (m & 15) * 4 + hi * 2;

    auto body = [&](int chunk) {
        int sb = (chunk & 1) * 2080 + rbase;
        float4 ca = Wr[sb];                        // ds_read_b128, conflict-free
        float4 cb = Wr[sb + 1];

        FU ah, al;                                 // split W -> A (hi, lo)
        splitpk(ca.x, ca.y, ah.u[0], al.u[0]);
        splitpk(ca.z, ca.w, ah.u[1], al.u[1]);
        splitpk(cb.x, cb.y, ah.u[2], al.u[2]);
        splitpk(cb.z, cb.w, ah.u[3], al.u[3]);

        f32x16 cf;                                 // u = W.x, 4-term bf16 split
        #pragma unroll
        for (int i = 0; i < 16; ++i) cf[i] = 0.f;
        cf = __builtin_amdgcn_mfma_f32_32x32x16_bf16(al.s, bl.s, cf, 0, 0, 0);
        cf = __builtin_amdgcn_mfma_f32_32x32x16_bf16(ah.s, bl.s, cf, 0, 0, 0);
        cf = __builtin_amdgcn_mfma_f32_32x32x16_bf16(al.s, bh.s, cf, 0, 0, 0);
        cf = __builtin_amdgcn_mfma_f32_32x32x16_bf16(ah.s, bh.s, cf, 0, 0, 0);

        float Lp0 = 0.f, Lp1 = 0.f;                // Lv[b,r'] = sum_o u*v
        #pragma unroll
        for (int reg = 0; reg < 8; ++reg)  Lp0 += cf[reg] * vf[reg];
        #pragma unroll
        for (int reg = 8; reg < 16; ++reg) Lp1 += cf[reg] * vf[reg];
        float Lv0 = Lp0 + __shfl_xor(Lp0, 32);     // partner has other 8 o's
        float Lv1 = Lp1 + __shfl_xor(Lp1, 32);
        float e0 = __expf(Lv0), e1 = __expf(Lv1);
        accZ += e0 + e1;                           // pair-duplicated (l<32 emits)
        #pragma unroll
        for (int reg = 0; reg < 8; ++reg)  accE[reg] += e0 * cf[reg];
        #pragma unroll
        for (int reg = 8; reg < 16; ++reg) accE[reg] += e1 * cf[reg];
    };

    #pragma unroll 2
    for (int chunk = 0; chunk < 30; ++chunk) {     // 32 chunks total
        asm volatile("s_waitcnt vmcnt(2)" ::: "memory");   // chunk k landed
        int sb = (chunk & 1) * 2080 + rbase;
        float4 ca = Wr[sb];
        float4 cb = Wr[sb + 1];
        // slot reuse safety: reads retired before the DMA refill below
        asm volatile("s_waitcnt lgkmcnt(0)" ::: "memory");
        __builtin_amdgcn_sched_barrier(0);
        STAGE(chunk & 1, chunk + 2);

        FU ah, al;
        splitpk(ca.x, ca.y, ah.u[0], al.u[0]);
        splitpk(ca.z, ca.w, ah.u[1], al.u[1]);
        splitpk(cb.x, cb.y, ah.u[2], al.u[2]);
        splitpk(cb.z, cb.w, ah.u[3], al.u[3]);

        f32x16 cf;
        #pragma unroll
        for (int i = 0; i < 16; ++i) cf[i] = 0.f;
        cf = __builtin_amdgcn_mfma_f32_32x32x16_bf16(al.s, bl.s, cf, 0, 0, 0);
        cf = __builtin_amdgcn_mfma_f32_32x32x16_bf16(ah.s, bl.s, cf, 0, 0, 0);
        cf = __builtin_amdgcn_mfma_f32_32x32x16_bf16(al.s, bh.s, cf, 0, 0, 0);
        cf = __builtin_amdgcn_mfma_f32_32x32x16_bf16(ah.s, bh.s, cf, 0, 0, 0);

        float Lp0 = 0.f, Lp1 = 0.f;
        #pragma unroll
        for (int reg = 0; reg < 8; ++reg)  Lp0 += cf[reg] * vf[reg];
        #pragma unroll
        for (int reg = 8; reg < 16; ++reg) Lp1 += cf[reg] * vf[reg];
        float Lv0 = Lp0 + __shfl_xor(Lp0, 32);
        float Lv1 = Lp1 + __shfl_xor(Lp1, 32);
        float e0 = __expf(Lv0), e1 = __expf(Lv1);
        accZ += e0 + e1;
        #pragma unroll
        for (int reg = 0; reg < 8; ++reg)  accE[reg] += e0 * cf[reg];
        #pragma unroll
        for (int reg = 8; reg < 16; ++reg) accE[reg] += e1 * cf[reg];
    }
    asm volatile("s_waitcnt vmcnt(2)" ::: "memory"); body(30);
    asm volatile("s_waitcnt vmcnt(0)" ::: "memory"); body(31);
#undef STAGE

    // epilogue: fold r' pairs (same o), one global atomic per (b, c, o)
    #pragma unroll
    for (int j = 0; j < 8; ++j) {
        int o = (j & 3) + 4 * hi + 8 * (j >> 2);
        atomicAdd(&E[m * 256 + c * 16 + o], accE[j] + accE[j + 8]);
    }
    if (l < 32) atomicAdd(&Z[m * 16 + c], accZ);
}

// ---------------------------------------------------------------------------
// launch
// ---------------------------------------------------------------------------
extern "C" void kernel_launch(void* const* d_in, const int* in_sizes, int n_in,
                              void* d_out, int out_size, void* d_ws, size_t ws_size,
                              hipStream_t stream) {
    const float* x = (const float*)d_in[0];        // 8192 floats
    const float* W = (const float*)d_in[1];        // 67108864 floats (256 MB)
    float* out = (float*)d_out;                    // 8192 floats
    float* ws = (float*)d_ws;

    float* wsum = ws + 0;          // 4096
    float* E2   = ws + 4096;       // 8192
    float* Z2   = ws + 12288;      // 512
    float* E3   = ws + 12800;      // 8192
    float* Z3   = ws + 20992;      // 512   (accumulated region ends at 21504)
    float* v1   = ws + 21504;      // 8192
    float* vs   = ws + 29696;      // 8192  (v1 + v2, input to pass 3)

    // zero accumulators with our own kernel
    k_zero<<<84, 256, 0, stream>>>(ws);            // 84*256 = 21504 floats

    // iter 1: uniform softmax -> v1 from Wsum (W pass 1)
    k_wsum<<<1024, 256, 0, stream>>>((const float4*)W, wsum);
    k_v1<<<32, 256, 0, stream>>>(wsum, x, v1);

    // iter 2 fused: L2 = <u, v1>, E2/Z2 accumulated in-pass (W pass 2)
    k_iter<<<256, 1024, 0, stream>>>(W, x, v1, E2, Z2);
    k_vout_vs<<<32, 256, 0, stream>>>(E2, Z2, v1, vs);   // vs = v1 + squash(E2/Z2)

    // iter 3 fused: L3 = <u, v1+v2> (linearity: no history buffer needed)
    k_iter<<<256, 1024, 0, stream>>>(W, x, vs, E3, Z3);
    k_vout<<<32, 256, 0, stream>>>(E3, Z3, out);         // out = squash(E3/Z3)
}

// Round 17
// 201.587 us; speedup vs baseline: 2.5225x; 2.5225x over previous
//
#include <hip/hip_runtime.h>
#include <math.h>

// B=32, R=16384, C=16, IC=16, OC=16, 3 routing iterations.
// x: (B,C,IC) fp32 [8192]; W: (R,C,OC,IC) fp32 [67108864 = 256 MB]; out: (B,C,OC) fp32.
//
// Algebra: logits are linear in v with the same u_hat each pass:
//   L2 = <u, v1>,  L3 = L2 + <u, v2> = <u, v1 + v2>
// so pass 3 is the SAME kernel as pass 2 fed with vs = v1 + v2 -> no L history.
//
// R17 = R16 resubmitted (R16's bench died with UnresponsiveContainer --
// infrastructure failure, no measurement).  R16 rationale:
// R11 winning structure (grid (64,16), wave-private FIFOs, fragment-
// permuted global src, counted vmcnt, zero main-loop barriers) with 4 ROWS
// per wave-chunk: 8 chunks x {2 A-fragments, 8 MFMAs} instead of 16 x
// {1 fragment, 4 MFMAs}.  Halves the wait-points (the 75us vs 21+21us floor
// gap is wait/compute ALTERNATION, not either pipe), raises in-flight to
// 8 KB/wave.  accE folds all rows (it is sum_r e*u) so register state is
// unchanged.  R12/R15 taught: keep the c-column grid (concurrent
// c-aggregation beats per-block contiguity); R15 also showed padded-65
// reads 4-way-conflict -- kept R11's consecutive-lane LDS reads (0 conflict).

typedef __attribute__((ext_vector_type(8)))  short short8;
typedef __attribute__((ext_vector_type(16))) float f32x16;

union FU { short8 s; unsigned int u[4]; };

typedef const __attribute__((address_space(1))) void GV;
typedef __attribute__((address_space(3))) void LV;

// Split two fp32 into packed bf16 (hi, lo) pairs: hi = RNE-bf16; lo covers
// the next 16 bits (round-half-up).  Product w*x reconstructed with 4 MFMA
// terms -> residual ~2^-16 relative.
__device__ __forceinline__ void splitpk(float a, float b,
                                        unsigned int& hp, unsigned int& lp) {
    unsigned int ua = __float_as_uint(a), ub = __float_as_uint(b);
    unsigned int ta = ua + 0x7FFFu + ((ua >> 16) & 1u);   // RNE to bf16
    unsigned int tb = ub + 0x7FFFu + ((ub >> 16) & 1u);
    hp = (ta >> 16) | (tb & 0xFFFF0000u);                 // (hi_b<<16)|hi_a
    float ha = __uint_as_float(ta & 0xFFFF0000u);
    float hb = __uint_as_float(tb & 0xFFFF0000u);
    unsigned int la = __float_as_uint(a - ha) + 0x8000u;  // round-half-up
    unsigned int lb = __float_as_uint(b - hb) + 0x8000u;
    lp = (la >> 16) | (lb & 0xFFFF0000u);
}

// ---------------------------------------------------------------------------
// K0: zero the accumulator region (wsum+E2+Z2+E3+Z3 = 21504 floats).
// ---------------------------------------------------------------------------
__global__ __launch_bounds__(256) void k_zero(float* __restrict__ ws) {
    ws[blockIdx.x * 256 + threadIdx.x] = 0.f;      // grid 84 x 256 = 21504
}

// ---------------------------------------------------------------------------
// K1: wsum[c,o,i] = sum_r W[r,c,o,i].  W = 16,777,216 float4s.
// ---------------------------------------------------------------------------
__global__ __launch_bounds__(256) void k_wsum(const float4* __restrict__ W4,
                                              float* __restrict__ wsum) {
    int gid = blockIdx.x * 256 + threadIdx.x;      // [0, 262144)
    float4 acc = {0.f, 0.f, 0.f, 0.f};
    int idx = gid;
    #pragma unroll
    for (int it = 0; it < 64; ++it) {              // 16777216 / 262144 = 64
        float4 w = W4[idx];
        acc.x += w.x; acc.y += w.y; acc.z += w.z; acc.w += w.w;
        idx += 262144;
    }
    int cls = gid & 1023;                          // (c,o,i4) within an r-block
    atomicAdd(&wsum[cls * 4 + 0], acc.x);
    atomicAdd(&wsum[cls * 4 + 1], acc.y);
    atomicAdd(&wsum[cls * 4 + 2], acc.z);
    atomicAdd(&wsum[cls * 4 + 3], acc.w);
}

// ---------------------------------------------------------------------------
// K2: s1 = (1/R) * wsum . x ;  v1 = squash(s1)  -> v1[b*256 + c*16 + o]
// ---------------------------------------------------------------------------
__global__ __launch_bounds__(256) void k_v1(const float* __restrict__ wsum,
                                            const float* __restrict__ x,
                                            float* __restrict__ v1) {
    int t = blockIdx.x * 256 + threadIdx.x;        // 0..8191
    int o = t & 15, c = (t >> 4) & 15, b = t >> 8;
    const float* xb = x + (b * 16 + c) * 16;
    const float* wr = wsum + (c * 16 + o) * 16;
    float s = 0.f;
    #pragma unroll
    for (int i = 0; i < 16; ++i) s += wr[i] * xb[i];
    s *= (1.0f / 16384.0f);
    float ns = s * s;
    #pragma unroll
    for (int d = 1; d < 16; d <<= 1) ns += __shfl_xor(ns, d);
    v1[t] = s * (sqrtf(ns) / (1.0f + ns));
}

// ---------------------------------------------------------------------------
// K4a: v2 = squash(E/Z); vs = v1 + v2   (input to pass 3)
// ---------------------------------------------------------------------------
__global__ __launch_bounds__(256) void k_vout_vs(const float* __restrict__ E,
                                                 const float* __restrict__ Z,
                                                 const float* __restrict__ v1,
                                                 float* __restrict__ vs) {
    int t = blockIdx.x * 256 + threadIdx.x;        // 0..8191
    float s = E[t] / Z[t >> 4];                    // t>>4 = b*16+c
    float ns = s * s;
    #pragma unroll
    for (int d = 1; d < 16; d <<= 1) ns += __shfl_xor(ns, d);
    vs[t] = v1[t] + s * (sqrtf(ns) / (1.0f + ns));
}

// ---------------------------------------------------------------------------
// K4b: out = squash(E/Z)
// ---------------------------------------------------------------------------
__global__ __launch_bounds__(256) void k_vout(const float* __restrict__ E,
                                              const float* __restrict__ Z,
                                              float* __restrict__ dst) {
    int t = blockIdx.x * 256 + threadIdx.x;        // 0..8191
    float s = E[t] / Z[t >> 4];
    float ns = s * s;
    #pragma unroll
    for (int d = 1; d < 16; d <<= 1) ns += __shfl_xor(ns, d);
    dst[t] = s * (sqrtf(ns) / (1.0f + ns));
}

// ---------------------------------------------------------------------------
// K3: MFMA routing pass, 4-rows-per-chunk wave-private pipeline.
//   Block (bx, c): rows [256bx, +256); wave wv owns rows
//   {chunk*32 + wv*4 + 0..3}; 8 chunks.  Per fragment p (rows 2p, 2p+1):
//   A (M=32 x K=16): lane m=l&31 -> (r'=m>>4, o=m&15); k-slice i=8*(l>>5)+j.
//   B (K=16 x N=32): lane n=b, chunk-invariant.  C: col=b, row-reg
//   o=(reg&3)+4hi+8((reg>>2)&1), r'=reg>>3 [verified R10].
//   Lv = 8 in-lane FMAs + ONE shfl_xor(32); accE[reg] += e*u folds rows.
// Staging: STAGE = 4 x global_load_lds (4 KB/wave); LDS [slot][wv][p][n][l]
// linear dest (consecutive-lane reads, 0 bank conflicts), fragment-permuted
// global src.  vmcnt per-wave -> NO main-loop barriers.  Ring-2 ledger:
// prologue stages 0,1 (8 issues); iter k: vmcnt(4) [k landed, k+1 flying]
// -> ds_read x4 -> lgkmcnt(0) -> STAGE(k&1, k+2) [k<=5] -> compute both
// fragments.  Tail: k=7 vmcnt(0).  LDS 68 KB -> 2 blocks/CU (R11 parity).
// Epilogue: ds-atomics to E_lds, one global atomic per thread.
// ---------------------------------------------------------------------------
__global__ __launch_bounds__(512)
void k_iter(const float* __restrict__ W,
            const float* __restrict__ x,
            const float* __restrict__ v,
            float* __restrict__ E,
            float* __restrict__ Z) {
    __shared__ float4 Wr[2 * 2048];                // 64 KB: 2 slots x 8wv x 4 x 64
    __shared__ float sV[512];                      // v[b][o] for this c
    __shared__ float E_lds[512];                   // block-level E[b][o]
    __shared__ float Z_lds[32];

    int c = blockIdx.y;
    int r0 = blockIdx.x * 256;
    int tid = threadIdx.x, wv = tid >> 6, l = tid & 63;
    int m  = l & 31;                               // A-row / b-col
    int hi = l >> 5;                               // k-slice select

    // stage v + zero the block reduction buffers
    { int b = tid >> 4, o = tid & 15;
      sV[tid] = v[b * 256 + c * 16 + o];
      E_lds[tid] = 0.f; }
    if (tid < 32) Z_lds[tid] = 0.f;

    // B-fragment (x), chunk-invariant: lane b=m, i = 8*hi + 0..7
    FU bh, bl;
    {
        const float4* xb = (const float4*)x + m * 64 + c * 4 + hi * 2;
        float4 x0 = xb[0], x1 = xb[1];
        splitpk(x0.x, x0.y, bh.u[0], bl.u[0]);
        splitpk(x0.z, x0.w, bh.u[1], bl.u[1]);
        splitpk(x1.x, x1.y, bh.u[2], bl.u[2]);
        splitpk(x1.z, x1.w, bh.u[3], bl.u[3]);
    }
    __syncthreads();                               // sV ready (written cross-lane)

    // v-fragment matching C rows: vf[reg] = v[b = m][o(reg)]
    float vf[16];
    #pragma unroll
    for (int reg = 0; reg < 16; ++reg) {
        int o = (reg & 3) + 4 * hi + 8 * ((reg >> 2) & 1);
        vf[reg] = sV[m * 16 + o];
    }

    float accE[16];
    #pragma unroll
    for (int reg = 0; reg < 16; ++reg) accE[reg] = 0.f;
    float accZ = 0.f;

    // pin vmcnt=0 so the counted waits below are exact (x/sV loads retired)
    asm volatile("s_waitcnt vmcnt(0)" ::: "memory");

    const float4* W4c = (const float4*)W + (size_t)c * 64;   // row r at +r*1024

    // STAGE: wave wv stages its 4 rows of chunk cn into slot sl.
    // Fragment p covers rows 2p+(m>>4); src per-lane fragment-permuted;
    // dest linear [sl][wv][p][n][lane].
#define STAGE(sl, cn) {                                                        \
        _Pragma("unroll")                                                      \
        for (int p = 0; p < 2; ++p) {                                          \
            const float4* s0 = W4c +                                           \
                (size_t)(r0 + (cn) * 32 + wv * 4 + p * 2 + (m >> 4)) * 1024 +  \
                (m & 15) * 4 + hi * 2;                                         \
            __builtin_amdgcn_global_load_lds((GV*)s0,                          \
                (LV*)&Wr[(sl) * 2048 + wv * 256 + p * 128], 16, 0, 0);         \
            __builtin_amdgcn_global_load_lds((GV*)(s0 + 1),                    \
                (LV*)&Wr[(sl) * 2048 + wv * 256 + p * 128 + 64], 16, 0, 0);    \
        } }

    STAGE(0, 0); STAGE(1, 1);                      // 8 issues (8 KB/wave) in flight

    #pragma unroll
    for (int chunk = 0; chunk < 8; ++chunk) {
        // retire THIS wave's loads for chunk k; k+1's stay in flight
        if (chunk < 7) asm volatile("s_waitcnt vmcnt(4)" ::: "memory");
        else           asm volatile("s_waitcnt vmcnt(0)" ::: "memory");

        int sb = (chunk & 1) * 2048 + wv * 256 + l;
        float4 w0a = Wr[sb],       w0b = Wr[sb + 64];    // fragment 0
        float4 w1a = Wr[sb + 128], w1b = Wr[sb + 192];   // fragment 1

        // slot reuse safety: reads retired before the DMA refill below
        asm volatile("s_waitcnt lgkmcnt(0)" ::: "memory");
        __builtin_amdgcn_sched_barrier(0);
        if (chunk <= 5) STAGE(chunk & 1, chunk + 2);

        #pragma unroll
        for (int p = 0; p < 2; ++p) {
            float4 ca = p ? w1a : w0a;
            float4 cb = p ? w1b : w0b;

            FU ah, al;                             // split W -> A (hi, lo)
            splitpk(ca.x, ca.y, ah.u[0], al.u[0]);
            splitpk(ca.z, ca.w, ah.u[1], al.u[1]);
            splitpk(cb.x, cb.y, ah.u[2], al.u[2]);
            splitpk(cb.z, cb.w, ah.u[3], al.u[3]);

            f32x16 cf;                             // u = W.x, 4-term bf16 split
            #pragma unroll
            for (int i = 0; i < 16; ++i) cf[i] = 0.f;
            cf = __builtin_amdgcn_mfma_f32_32x32x16_bf16(al.s, bl.s, cf, 0, 0, 0);
            cf = __builtin_amdgcn_mfma_f32_32x32x16_bf16(ah.s, bl.s, cf, 0, 0, 0);
            cf = __builtin_amdgcn_mfma_f32_32x32x16_bf16(al.s, bh.s, cf, 0, 0, 0);
            cf = __builtin_amdgcn_mfma_f32_32x32x16_bf16(ah.s, bh.s, cf, 0, 0, 0);

            float Lp0 = 0.f, Lp1 = 0.f;            // Lv[b,r'] = sum_o u*v
            #pragma unroll
            for (int reg = 0; reg < 8; ++reg)  Lp0 += cf[reg] * vf[reg];
            #pragma unroll
            for (int reg = 8; reg < 16; ++reg) Lp1 += cf[reg] * vf[reg];
            float Lv0 = Lp0 + __shfl_xor(Lp0, 32); // partner has other 8 o's
            float Lv1 = Lp1 + __shfl_xor(Lp1, 32);
            float e0 = __expf(Lv0), e1 = __expf(Lv1);
            accZ += e0 + e1;                       // pair-duplicated (l<32 emits)
            #pragma unroll
            for (int reg = 0; reg < 8; ++reg)  accE[reg] += e0 * cf[reg];
            #pragma unroll
            for (int reg = 8; reg < 16; ++reg) accE[reg] += e1 * cf[reg];
        }
    }
#undef STAGE

    // fold r' pairs (same o), reduce across waves via LDS atomics
    #pragma unroll
    for (int j = 0; j < 8; ++j) {
        int o = (j & 3) + 4 * hi + 8 * (j >> 2);
        atomicAdd(&E_lds[m * 16 + o], accE[j] + accE[j + 8]);
    }
    if (l < 32) atomicAdd(&Z_lds[m], accZ);
    __syncthreads();

    atomicAdd(&E[(tid >> 4) * 256 + c * 16 + (tid & 15)], E_lds[tid]);
    if (tid < 32) atomicAdd(&Z[tid * 16 + c], Z_lds[tid]);
}

// ---------------------------------------------------------------------------
// launch
// ---------------------------------------------------------------------------
extern "C" void kernel_launch(void* const* d_in, const int* in_sizes, int n_in,
                              void* d_out, int out_size, void* d_ws, size_t ws_size,
                              hipStream_t stream) {
    const float* x = (const float*)d_in[0];        // 8192 floats
    const float* W = (const float*)d_in[1];        // 67108864 floats (256 MB)
    float* out = (float*)d_out;                    // 8192 floats
    float* ws = (float*)d_ws;

    float* wsum = ws + 0;          // 4096
    float* E2   = ws + 4096;       // 8192
    float* Z2   = ws + 12288;      // 512
    float* E3   = ws + 12800;      // 8192
    float* Z3   = ws + 20992;      // 512   (accumulated region ends at 21504)
    float* v1   = ws + 21504;      // 8192
    float* vs   = ws + 29696;      // 8192  (v1 + v2, input to pass 3)

    // zero accumulators with our own kernel
    k_zero<<<84, 256, 0, stream>>>(ws);            // 84*256 = 21504 floats

    // iter 1: uniform softmax -> v1 from Wsum (W pass 1)
    k_wsum<<<1024, 256, 0, stream>>>((const float4*)W, wsum);
    k_v1<<<32, 256, 0, stream>>>(wsum, x, v1);

    // iter 2 fused: L2 = <u, v1>, E2/Z2 accumulated in-pass (W pass 2)
    k_iter<<<dim3(64, 16), 512, 0, stream>>>(W, x, v1, E2, Z2);
    k_vout_vs<<<32, 256, 0, stream>>>(E2, Z2, v1, vs);   // vs = v1 + squash(E2/Z2)

    // iter 3 fused: L3 = <u, v1+v2> (linearity: no history buffer needed)
    k_iter<<<dim3(64, 16), 512, 0, stream>>>(W, x, vs, E3, Z3);
    k_vout<<<32, 256, 0, stream>>>(E3, Z3, out);         // out = squash(E3/Z3)
}